// Round 3
// baseline (1031.003 us; speedup 1.0000x reference)
//
#include <hip/hip_runtime.h>
#include <math.h>

#define BKS 60      // B*K sequences
#define TL  1000    // T
#define NF  128     // N features
#define SD  12      // state dim S
#define NCH 32      // scan chunks of 32 (ap/hfb/hinit granularity, unchanged)
#define NTOK (BKS*TL)
#define CL2 64      // front/back block token count (2 scan chunks)
#define NCB 16      // 64-token chunks per sequence
#define CROSS_NBLK ((NTOK + CL2 - 1)/CL2)   // 938

// row-keyed XOR swizzle (bits 2..4 of float col index) for [row][128] tiles
// where wave lanes span 8 rows 8-apart (t>>3 distinguishes them).
#define SRK(row) ((((row)>>3)&7)<<2)

__device__ __forceinline__ float siluf(float x){ return x / (1.f + __expf(-x)); }
__device__ __forceinline__ float softplusf(float x){
  if (x > 20.f) return x;
  float e = __expf(x);
  return (x < -20.f) ? e : __logf(1.f + e);
}

// ---- K0: x (B,N,T,K) -> seq (B*K, T, N), one block per (b,t)
__global__ __launch_bounds__(256) void k_ingest(const float* __restrict__ x, float* __restrict__ seq){
  const int b = blockIdx.x / TL, t = blockIdx.x % TL;
  __shared__ float tile[30*NF];
  for (int e = threadIdx.x; e < 30*NF; e += 256){
    int n = e / 30, k = e - n*30;
    tile[k*NF + n] = x[((size_t)(b*NF + n)*TL + t)*30 + k];
  }
  __syncthreads();
  const size_t base = ((size_t)b*30)*TL*NF + (size_t)t*NF;
  for (int e = threadIdx.x; e < 30*NF; e += 256){
    int k = e >> 7, n = e & 127;
    seq[base + (size_t)k*TL*NF + n] = tile[e];
  }
}

// ---- k_front: LN -> in_proj (256 outs) -> conv+silu -> xproj -> dt -> scan pass1.
// One 64-token chunk of one sequence per block. 960 blocks, 256 threads.
// LDS exactly 40960 B (4 blocks/CU). t-major x in LDS; w read from global (L1-hot).
// Single barrier inside the GEMM (vs 32 in the old staged version).
__global__ __launch_bounds__(256,4) void k_front(
    const float* __restrict__ seq,
    const float* __restrict__ lnw, const float* __restrict__ lnb,
    const float* __restrict__ iw, const float* __restrict__ ib,
    const float* __restrict__ cw, const float* __restrict__ cb,
    const float* __restrict__ xw,
    const float* __restrict__ dw, const float* __restrict__ db,
    const float* __restrict__ alog,
    float* __restrict__ zb, float* __restrict__ xcc,
    float* __restrict__ dcb, float* __restrict__ bcb,
    float* __restrict__ ap, float* __restrict__ hfb){
  __shared__ float smem[10240];          // 40960 B
  float* xs   = smem;                    // [64][128] LN out, t-major, SRK-swizzled
  float* xh   = smem + 8192;             // [3][128] halo LN out (raw)
  float* sxcr = smem;                    // [67][128] raw xc (aliases xs+xh after GEMM)
  float* sxc  = smem;                    // [64][128] conv+silu out (in-place, SRK-swizzled)
  float* sdbc = smem + 8192;             // [64][32] dbc (after conv, rows 64..66 dead)

  const int bid = blockIdx.x;
  const int sq = bid >> 4, cb2 = bid & 15;
  const int t0 = cb2 * CL2;
  const int lim = (TL - t0 < CL2) ? (TL - t0) : CL2;
  const int tid = threadIdx.x;

  // ---- P0: LayerNorm for 64 main tokens + 3 halo tokens
  {
    const int j = tid >> 4, l16 = tid & 15;
    const float4 w0 = *(const float4*)(lnw + l16*8);
    const float4 w1 = *(const float4*)(lnw + l16*8 + 4);
    const float4 b0 = *(const float4*)(lnb + l16*8);
    const float4 b1 = *(const float4*)(lnb + l16*8 + 4);
    const float lw[8] = {w0.x,w0.y,w0.z,w0.w, w1.x,w1.y,w1.z,w1.w};
    const float lb[8] = {b0.x,b0.y,b0.z,b0.w, b1.x,b1.y,b1.z,b1.w};
    for (int it = 0; it < 4; ++it){
      const int t = j + 16*it;
      const bool valid = (t < lim);
      float v[8]; float s = 0.f, s2 = 0.f;
      if (valid){
        const float* sp = seq + ((size_t)sq*TL + t0 + t)*NF + l16*8;
        const float4 a0 = *(const float4*)sp;
        const float4 a1 = *(const float4*)(sp + 4);
        v[0]=a0.x; v[1]=a0.y; v[2]=a0.z; v[3]=a0.w;
        v[4]=a1.x; v[5]=a1.y; v[6]=a1.z; v[7]=a1.w;
        #pragma unroll
        for (int i = 0; i < 8; ++i){ s += v[i]; s2 += v[i]*v[i]; }
      } else {
        #pragma unroll
        for (int i = 0; i < 8; ++i) v[i] = 0.f;
      }
      #pragma unroll
      for (int m = 1; m < 16; m <<= 1){ s += __shfl_xor(s, m, 64); s2 += __shfl_xor(s2, m, 64); }
      const float mean = s * (1.f/128.f);
      const float rstd = rsqrtf(s2*(1.f/128.f) - mean*mean + 1e-5f);
      const int sk = SRK(t);
      float o[8];
      #pragma unroll
      for (int i = 0; i < 8; ++i)
        o[i] = valid ? ((v[i]-mean)*rstd*lw[i] + lb[i]) : 0.f;
      *(float4*)&xs[t*NF + ((l16*8)     ^ sk)] = make_float4(o[0],o[1],o[2],o[3]);
      *(float4*)&xs[t*NF + ((l16*8 + 4) ^ sk)] = make_float4(o[4],o[5],o[6],o[7]);
    }
    // halo: tokens t0-3..t0-1 -> xh rows 0..2 (raw layout)
    if (j < 3){
      const int tg2 = t0 - 3 + j;
      const bool valid = (tg2 >= 0);
      float v[8]; float s = 0.f, s2 = 0.f;
      if (valid){
        const float* sp = seq + ((size_t)sq*TL + tg2)*NF + l16*8;
        const float4 a0 = *(const float4*)sp;
        const float4 a1 = *(const float4*)(sp + 4);
        v[0]=a0.x; v[1]=a0.y; v[2]=a0.z; v[3]=a0.w;
        v[4]=a1.x; v[5]=a1.y; v[6]=a1.z; v[7]=a1.w;
        #pragma unroll
        for (int i = 0; i < 8; ++i){ s += v[i]; s2 += v[i]*v[i]; }
      } else {
        #pragma unroll
        for (int i = 0; i < 8; ++i) v[i] = 0.f;
      }
      #pragma unroll
      for (int m = 1; m < 16; m <<= 1){ s += __shfl_xor(s, m, 64); s2 += __shfl_xor(s2, m, 64); }
      const float mean = s * (1.f/128.f);
      const float rstd = rsqrtf(s2*(1.f/128.f) - mean*mean + 1e-5f);
      float o[8];
      #pragma unroll
      for (int i = 0; i < 8; ++i)
        o[i] = valid ? ((v[i]-mean)*rstd*lw[i] + lb[i]) : 0.f;
      *(float4*)&xh[j*NF + l16*8]     = make_float4(o[0],o[1],o[2],o[3]);
      *(float4*)&xh[j*NF + l16*8 + 4] = make_float4(o[4],o[5],o[6],o[7]);
    }
  }
  __syncthreads();

  // ---- P1: in_proj GEMM. og owns 8 output rows (og<16 -> xc, og>=16 -> z), tg owns 8 tokens.
  const int og = tid >> 3;     // 0..31
  const int tg = tid & 7;      // 0..7
  float acc[8][8];
  float hacc[8];
  #pragma unroll
  for (int o = 0; o < 8; ++o){
    hacc[o] = 0.f;
    #pragma unroll
    for (int j = 0; j < 8; ++j) acc[o][j] = 0.f;
  }
  const bool do_halo = (og < 16) && (tg < 3);
  const int hrow = (tg < 3) ? tg : 2;
  const float* wb = iw + (size_t)(og*8)*NF;
  for (int k4 = 0; k4 < 32; ++k4){
    const int kk = k4*4;
    float4 xv[8];
    #pragma unroll
    for (int j = 0; j < 8; ++j)
      xv[j] = *(const float4*)&xs[(tg*8+j)*NF + (kk ^ (tg<<2))];
    const float4 xh4 = *(const float4*)&xh[hrow*NF + kk];
    #pragma unroll
    for (int o = 0; o < 8; ++o){
      const float4 w4 = *(const float4*)(wb + (size_t)o*NF + kk);
      #pragma unroll
      for (int j = 0; j < 8; ++j){
        acc[o][j] = fmaf(w4.x, xv[j].x, acc[o][j]);
        acc[o][j] = fmaf(w4.y, xv[j].y, acc[o][j]);
        acc[o][j] = fmaf(w4.z, xv[j].z, acc[o][j]);
        acc[o][j] = fmaf(w4.w, xv[j].w, acc[o][j]);
      }
      if (do_halo){
        hacc[o] = fmaf(w4.x, xh4.x, hacc[o]);
        hacc[o] = fmaf(w4.y, xh4.y, hacc[o]);
        hacc[o] = fmaf(w4.z, xh4.z, hacc[o]);
        hacc[o] = fmaf(w4.w, xh4.w, hacc[o]);
      }
    }
  }
  float bo[8];
  #pragma unroll
  for (int i = 0; i < 8; ++i) bo[i] = ib[og*8 + i];   // rows 128.. for og>=16 automatically
  // z epilogue (register-only, before barrier)
  if (og >= 16){
    #pragma unroll
    for (int j = 0; j < 8; ++j){
      const int lt = tg*8 + j;
      if (lt >= lim) continue;
      float* dst = zb + ((size_t)sq*TL + t0 + lt)*NF + (og-16)*8;
      *(float4*)dst       = make_float4(acc[0][j]+bo[0], acc[1][j]+bo[1], acc[2][j]+bo[2], acc[3][j]+bo[3]);
      *(float4*)(dst + 4) = make_float4(acc[4][j]+bo[4], acc[5][j]+bo[5], acc[6][j]+bo[6], acc[7][j]+bo[7]);
    }
  }
  __syncthreads();   // xs/xh dead -> sxcr may be written
  if (og < 16){
    #pragma unroll
    for (int j = 0; j < 8; ++j){
      const int row = tg*8 + j + 3;
      const int sk = SRK(row);
      *(float4*)&sxcr[row*NF + ((og*8)     ^ sk)] = make_float4(acc[0][j]+bo[0], acc[1][j]+bo[1], acc[2][j]+bo[2], acc[3][j]+bo[3]);
      *(float4*)&sxcr[row*NF + ((og*8 + 4) ^ sk)] = make_float4(acc[4][j]+bo[4], acc[5][j]+bo[5], acc[6][j]+bo[6], acc[7][j]+bo[7]);
    }
    if (tg < 3){
      const bool hvalid = (t0 - 3 + tg) >= 0;
      // SRK(tg)=0 for tg<3 -> raw
      float4 h0 = hvalid ? make_float4(hacc[0]+bo[0],hacc[1]+bo[1],hacc[2]+bo[2],hacc[3]+bo[3]) : make_float4(0,0,0,0);
      float4 h1 = hvalid ? make_float4(hacc[4]+bo[4],hacc[5]+bo[5],hacc[6]+bo[6],hacc[7]+bo[7]) : make_float4(0,0,0,0);
      *(float4*)&sxcr[tg*NF + og*8]     = h0;
      *(float4*)&sxcr[tg*NF + og*8 + 4] = h1;
    }
  }
  __syncthreads();

  // ---- P2: conv + silu, in place (two halves; reg-stage inputs, barrier, write)
  for (int half = 0; half < 2; ++half){
    float4 xin[4][4];
    #pragma unroll
    for (int i = 0; i < 4; ++i){
      const int e4 = tid + i*256;
      const int j2 = half*32 + (e4 >> 5);
      const int n4 = (e4 & 31) << 2;
      #pragma unroll
      for (int q = 0; q < 4; ++q){
        const int row = j2 + q;
        xin[i][q] = *(const float4*)&sxcr[row*NF + (n4 ^ SRK(row))];
      }
    }
    __syncthreads();
    #pragma unroll
    for (int i = 0; i < 4; ++i){
      const int e4 = tid + i*256;
      const int j2 = half*32 + (e4 >> 5);
      const int n4 = (e4 & 31) << 2;
      const float4 c0 = *(const float4*)(cw + (size_t)(n4+0)*4);
      const float4 c1 = *(const float4*)(cw + (size_t)(n4+1)*4);
      const float4 c2 = *(const float4*)(cw + (size_t)(n4+2)*4);
      const float4 c3 = *(const float4*)(cw + (size_t)(n4+3)*4);
      float4 a = *(const float4*)(cb + n4);
      a.x = fmaf(xin[i][3].x, c0.w, fmaf(xin[i][2].x, c0.z, fmaf(xin[i][1].x, c0.y, fmaf(xin[i][0].x, c0.x, a.x))));
      a.y = fmaf(xin[i][3].y, c1.w, fmaf(xin[i][2].y, c1.z, fmaf(xin[i][1].y, c1.y, fmaf(xin[i][0].y, c1.x, a.y))));
      a.z = fmaf(xin[i][3].z, c2.w, fmaf(xin[i][2].z, c2.z, fmaf(xin[i][1].z, c2.y, fmaf(xin[i][0].z, c2.x, a.z))));
      a.w = fmaf(xin[i][3].w, c3.w, fmaf(xin[i][2].w, c3.z, fmaf(xin[i][1].w, c3.y, fmaf(xin[i][0].w, c3.x, a.w))));
      a.x = siluf(a.x); a.y = siluf(a.y); a.z = siluf(a.z); a.w = siluf(a.w);
      *(float4*)&sxc[j2*NF + (n4 ^ SRK(j2))] = a;
      if (j2 < lim) *(float4*)(xcc + ((size_t)sq*TL + t0 + j2)*NF + n4) = a;
    }
    __syncthreads();
  }

  // ---- P3: xproj -> sdbc[64][32] (w from global)
  {
    const int og2 = tid >> 5;   // 0..7, outs og2*4..+3
    const int tg2 = tid & 31;   // tokens tg2*2, tg2*2+1
    const int ta = tg2*2, tb = tg2*2 + 1;
    const int ska = SRK(ta), skb = SRK(tb);
    float pa[4][2];
    #pragma unroll
    for (int o = 0; o < 4; ++o){ pa[o][0] = 0.f; pa[o][1] = 0.f; }
    const float* xwb = xw + (size_t)(og2*4)*NF;
    for (int k4 = 0; k4 < 32; ++k4){
      const int kk = k4*4;
      const float4 xv0 = *(const float4*)&sxc[ta*NF + (kk ^ ska)];
      const float4 xv1 = *(const float4*)&sxc[tb*NF + (kk ^ skb)];
      #pragma unroll
      for (int o = 0; o < 4; ++o){
        const float4 w4 = *(const float4*)(xwb + (size_t)o*NF + kk);
        pa[o][0] = fmaf(w4.w, xv0.w, fmaf(w4.z, xv0.z, fmaf(w4.y, xv0.y, fmaf(w4.x, xv0.x, pa[o][0]))));
        pa[o][1] = fmaf(w4.w, xv1.w, fmaf(w4.z, xv1.z, fmaf(w4.y, xv1.y, fmaf(w4.x, xv1.x, pa[o][1]))));
      }
    }
    *(float4*)&sdbc[ta*32 + og2*4] = make_float4(pa[0][0],pa[1][0],pa[2][0],pa[3][0]);
    *(float4*)&sdbc[tb*32 + og2*4] = make_float4(pa[0][1],pa[1][1],pa[2][1],pa[3][1]);
  }
  __syncthreads();

  // ---- P4: dcb/bcb global writes + scan pass1 (dt computed in-thread)
  if (tid < 128){
    const int t = tid >> 1, q = tid & 1;
    if (t < lim)
      *(float4*)(dcb + ((size_t)sq*TL + t0 + t)*8 + q*4) = *(const float4*)&sdbc[t*32 + q*4];
  }
  for (int e = tid; e < 384; e += 256){
    const int t = e / 6, q = e - t*6;
    if (t < lim)
      *(float4*)(bcb + ((size_t)sq*TL + t0 + t)*24 + q*4) = *(const float4*)&sdbc[t*32 + 8 + q*4];
  }
  {
    const int n = tid & 127, ch = tid >> 7;
    float Av[SD];
    {
      const float4 a0 = *(const float4*)(alog + (size_t)n*SD);
      const float4 a1 = *(const float4*)(alog + (size_t)n*SD + 4);
      const float4 a2 = *(const float4*)(alog + (size_t)n*SD + 8);
      const float t_[SD] = {a0.x,a0.y,a0.z,a0.w, a1.x,a1.y,a1.z,a1.w, a2.x,a2.y,a2.z,a2.w};
      #pragma unroll
      for (int s = 0; s < SD; ++s) Av[s] = -__expf(t_[s]);
    }
    const float4 dw0 = *(const float4*)(dw + (size_t)n*8);
    const float4 dw1 = *(const float4*)(dw + (size_t)n*8 + 4);
    const float dbn = db[n];
    int steps = lim - ch*32; if (steps < 0) steps = 0; if (steps > 32) steps = 32;
    float h[SD]; float dts = 0.f;
    #pragma unroll
    for (int s = 0; s < SD; ++s) h[s] = 0.f;
    for (int tt = 0; tt < steps; ++tt){
      const int t = ch*32 + tt;
      const float4 q0 = *(const float4*)&sdbc[t*32];
      const float4 q1 = *(const float4*)&sdbc[t*32 + 4];
      float da = dbn;
      da = fmaf(q0.x,dw0.x, da); da = fmaf(q0.y,dw0.y, da);
      da = fmaf(q0.z,dw0.z, da); da = fmaf(q0.w,dw0.w, da);
      da = fmaf(q1.x,dw1.x, da); da = fmaf(q1.y,dw1.y, da);
      da = fmaf(q1.z,dw1.z, da); da = fmaf(q1.w,dw1.w, da);
      const float dtv = softplusf(da);
      const float xcv = sxc[t*NF + (n ^ SRK(t))];
      const float4 B0 = *(const float4*)&sdbc[t*32 + 8];
      const float4 B1 = *(const float4*)&sdbc[t*32 + 12];
      const float4 B2 = *(const float4*)&sdbc[t*32 + 16];
      const float Bv[SD] = {B0.x,B0.y,B0.z,B0.w, B1.x,B1.y,B1.z,B1.w, B2.x,B2.y,B2.z,B2.w};
      const float dx = dtv * xcv;
      dts += dtv;
      #pragma unroll
      for (int s = 0; s < SD; ++s){
        const float dA = __expf(dtv*Av[s]);
        h[s] = fmaf(dA, h[s], dx*Bv[s]);
      }
    }
    const size_t base = ((size_t)(sq*NCH + cb2*2 + ch))*SD*NF + n;
    #pragma unroll
    for (int s = 0; s < SD; ++s){
      ap [base + s*NF] = __expf(Av[s]*dts);
      hfb[base + s*NF] = h[s];
    }
  }
}

// ---- K3b: sequential combine across chunks (unchanged)
__global__ __launch_bounds__(128) void k_scan_combine(
    const float* __restrict__ ap, const float* __restrict__ hfb, float* __restrict__ hinit){
  const int sq = blockIdx.x;
  const int n = threadIdx.x;
  float h[SD];
  #pragma unroll
  for (int s = 0; s < SD; ++s) h[s] = 0.f;
  for (int c = 0; c < NCH; ++c){
    const size_t base = ((size_t)sq*NCH + c)*SD*NF + n;
    #pragma unroll
    for (int s = 0; s < SD; ++s){
      hinit[base + s*NF] = h[s];
      h[s] = fmaf(ap[base + s*NF], h[s], hfb[base + s*NF]);
    }
  }
}

// ---- k_back: scan pass2 (y -> LDS) -> output GEMM -> seq += y@ow^T+ob.
// One 64-token chunk per block (2 scan chunks in parallel). 960 blocks.
__global__ __launch_bounds__(256,4) void k_back(
    const float* __restrict__ dcb, const float* __restrict__ bcb,
    const float* __restrict__ xcc, const float* __restrict__ zb,
    const float* __restrict__ dw, const float* __restrict__ db,
    const float* __restrict__ alog, const float* __restrict__ hinit,
    const float* __restrict__ Dv,
    const float* __restrict__ ow, const float* __restrict__ ob,
    float* __restrict__ seq){
  __shared__ float xs[CL2*NF];   // 32768 B; y (SRK-swizzled); aliased as partial buf pb
  const int bid = blockIdx.x;
  const int sq = bid >> 4, cb2 = bid & 15;
  const int t0 = cb2 * CL2;
  const int lim = (TL - t0 < CL2) ? (TL - t0) : CL2;
  const int tid = threadIdx.x;

  // ---- P0: scan pass2 + gate, write y to LDS
  {
    const int n = tid & 127, ch = tid >> 7;
    float Av[SD];
    {
      const float4 a0 = *(const float4*)(alog + (size_t)n*SD);
      const float4 a1 = *(const float4*)(alog + (size_t)n*SD + 4);
      const float4 a2 = *(const float4*)(alog + (size_t)n*SD + 8);
      const float t_[SD] = {a0.x,a0.y,a0.z,a0.w, a1.x,a1.y,a1.z,a1.w, a2.x,a2.y,a2.z,a2.w};
      #pragma unroll
      for (int s = 0; s < SD; ++s) Av[s] = -__expf(t_[s]);
    }
    const float4 dw0 = *(const float4*)(dw + (size_t)n*8);
    const float4 dw1 = *(const float4*)(dw + (size_t)n*8 + 4);
    const float dbn = db[n];
    const float dvn = Dv[n];
    float h[SD];
    {
      const size_t hb = ((size_t)(sq*NCH + cb2*2 + ch))*SD*NF + n;
      #pragma unroll
      for (int s = 0; s < SD; ++s) h[s] = hinit[hb + s*NF];
    }
    int steps = lim - ch*32; if (steps < 0) steps = 0; if (steps > 32) steps = 32;
    for (int tt = 0; tt < steps; ++tt){
      const int t = ch*32 + tt;
      const size_t gt = (size_t)sq*TL + t0 + t;
      const float4 d0 = *(const float4*)(dcb + gt*8);
      const float4 d1 = *(const float4*)(dcb + gt*8 + 4);
      float da = dbn;
      da = fmaf(d0.x,dw0.x, da); da = fmaf(d0.y,dw0.y, da);
      da = fmaf(d0.z,dw0.z, da); da = fmaf(d0.w,dw0.w, da);
      da = fmaf(d1.x,dw1.x, da); da = fmaf(d1.y,dw1.y, da);
      da = fmaf(d1.z,dw1.z, da); da = fmaf(d1.w,dw1.w, da);
      const float dtv = softplusf(da);
      const float xcv = xcc[gt*NF + n];
      const float zv  = zb [gt*NF + n];
      const float4 B0 = *(const float4*)(bcb + gt*24);
      const float4 B1 = *(const float4*)(bcb + gt*24 + 4);
      const float4 B2 = *(const float4*)(bcb + gt*24 + 8);
      const float4 C0 = *(const float4*)(bcb + gt*24 + 12);
      const float4 C1 = *(const float4*)(bcb + gt*24 + 16);
      const float4 C2 = *(const float4*)(bcb + gt*24 + 20);
      const float Bv[SD] = {B0.x,B0.y,B0.z,B0.w, B1.x,B1.y,B1.z,B1.w, B2.x,B2.y,B2.z,B2.w};
      const float Cv[SD] = {C0.x,C0.y,C0.z,C0.w, C1.x,C1.y,C1.z,C1.w, C2.x,C2.y,C2.z,C2.w};
      const float dx = dtv * xcv;
      float y = 0.f;
      #pragma unroll
      for (int s = 0; s < SD; ++s){
        const float dA = __expf(dtv*Av[s]);
        h[s] = fmaf(dA, h[s], dx*Bv[s]);
        y = fmaf(h[s], Cv[s], y);
      }
      const float yf = fmaf(dvn, xcv, y) * siluf(zv);
      xs[t*NF + (n ^ SRK(t))] = yf;
    }
  }
  // zero rows beyond lim (last chunk only)
  if (lim < CL2){
    for (int e = tid; e < (CL2 - lim)*NF; e += 256) xs[lim*NF + e] = 0.f;
  }
  __syncthreads();

  // ---- P1: GEMM seq += y @ ow^T + ob.  8o x 8t tile, K split 2 ways.
  const int slot = tid & 127, kq = tid >> 7;
  const int og = slot >> 3, tg = slot & 7;   // og: 16 groups x 8 outs; tg: 8 groups x 8 tokens
  float facc[8][8];
  #pragma unroll
  for (int o = 0; o < 8; ++o)
    #pragma unroll
    for (int j = 0; j < 8; ++j) facc[o][j] = 0.f;
  const float* owb = ow + (size_t)(og*8)*NF;
  for (int k4 = 0; k4 < 16; ++k4){
    const int kk = kq*64 + k4*4;
    float4 xv[8];
    #pragma unroll
    for (int j = 0; j < 8; ++j)
      xv[j] = *(const float4*)&xs[(tg*8+j)*NF + (kk ^ (tg<<2))];
    #pragma unroll
    for (int o = 0; o < 8; ++o){
      const float4 w4 = *(const float4*)(owb + (size_t)o*NF + kk);
      #pragma unroll
      for (int j = 0; j < 8; ++j){
        facc[o][j] = fmaf(w4.x, xv[j].x, facc[o][j]);
        facc[o][j] = fmaf(w4.y, xv[j].y, facc[o][j]);
        facc[o][j] = fmaf(w4.z, xv[j].z, facc[o][j]);
        facc[o][j] = fmaf(w4.w, xv[j].w, facc[o][j]);
      }
    }
  }
  __syncthreads();   // xs (y) dead -> partial buffer
  float* pb = xs;
  const int pkey = (slot & 15) << 2;
  if (kq == 1){
    #pragma unroll
    for (int o = 0; o < 8; ++o){
      #pragma unroll
      for (int t4 = 0; t4 < 2; ++t4){
        *(float4*)&pb[slot*64 + ((o*8 + t4*4) ^ pkey)] =
          make_float4(facc[o][t4*4+0], facc[o][t4*4+1], facc[o][t4*4+2], facc[o][t4*4+3]);
      }
    }
  }
  __syncthreads();
  if (kq == 0){
    float bo[8];
    #pragma unroll
    for (int i = 0; i < 8; ++i) bo[i] = ob[og*8 + i];
    #pragma unroll
    for (int t4 = 0; t4 < 2; ++t4){
      float4 pv[8];
      #pragma unroll
      for (int o = 0; o < 8; ++o)
        pv[o] = *(const float4*)&pb[slot*64 + ((o*8 + t4*4) ^ pkey)];
      #pragma unroll
      for (int u = 0; u < 4; ++u){
        const int lt = tg*8 + t4*4 + u;
        if (lt >= lim) continue;
        float* dst = seq + ((size_t)sq*TL + t0 + lt)*NF + og*8;
        float4 s0 = *(float4*)dst;
        float4 s1 = *(float4*)(dst + 4);
        const float p0 = ((const float*)&pv[0])[u], p1 = ((const float*)&pv[1])[u];
        const float p2 = ((const float*)&pv[2])[u], p3 = ((const float*)&pv[3])[u];
        const float p4 = ((const float*)&pv[4])[u], p5 = ((const float*)&pv[5])[u];
        const float p6 = ((const float*)&pv[6])[u], p7 = ((const float*)&pv[7])[u];
        s0.x += facc[0][t4*4+u] + p0 + bo[0];
        s0.y += facc[1][t4*4+u] + p1 + bo[1];
        s0.z += facc[2][t4*4+u] + p2 + bo[2];
        s0.w += facc[3][t4*4+u] + p3 + bo[3];
        s1.x += facc[4][t4*4+u] + p4 + bo[4];
        s1.y += facc[5][t4*4+u] + p5 + bo[5];
        s1.z += facc[6][t4*4+u] + p6 + bo[6];
        s1.w += facc[7][t4*4+u] + p7 + bo[7];
        *(float4*)dst = s0;
        *(float4*)(dst + 4) = s1;
      }
    }
  }
}

// ---- k_cross: cross GEMM -> LN -> gelu -> +main -> LN -> transposed out. 64 tok/block.
__global__ __launch_bounds__(256) void k_cross(
    const float* __restrict__ seq,
    const float* __restrict__ cbw, const float* __restrict__ cbb,
    const float* __restrict__ clnw, const float* __restrict__ clnb,
    const float* __restrict__ flnw, const float* __restrict__ flnb,
    float* __restrict__ out){
  __shared__ float xs[CL2*NF];   // main (gathered), t-major raw; aliased as fs after LN
  const int tid = threadIdx.x;
  const int tok0 = blockIdx.x * CL2;

  // stage main (gather)
  #pragma unroll
  for (int i = 0; i < 8; ++i){
    const int nq = (tid & 15) + ((i >> 2) << 4);        // 0..31
    const int r  = ((tid >> 4) & 15) + ((i & 3) << 4);  // 0..63
    const int tok = tok0 + r;
    float4 v = make_float4(0.f,0.f,0.f,0.f);
    if (tok < NTOK){
      const int b = tok / 30000, rr = tok - b*30000;
      const int t = rr / 30, k = rr - t*30;
      v = *(const float4*)(seq + ((size_t)(b*30 + k)*TL + t)*NF + nq*4);
    }
    *(float4*)&xs[r*NF + nq*4] = v;
  }
  __syncthreads();

  const int o4g = tid & 31, t8 = tid >> 5;   // 4 outs, 8 tokens per thread
  float acc[4][8];
  #pragma unroll
  for (int o = 0; o < 4; ++o)
    #pragma unroll
    for (int j = 0; j < 8; ++j) acc[o][j] = 0.f;
  const float* wb = cbw + (size_t)(o4g*4)*NF;
  for (int k4 = 0; k4 < 32; ++k4){
    const int kk = k4*4;
    float4 xv[8];
    #pragma unroll
    for (int j = 0; j < 8; ++j)
      xv[j] = *(const float4*)&xs[(t8*8+j)*NF + kk];
    #pragma unroll
    for (int o = 0; o < 4; ++o){
      const float4 w4 = *(const float4*)(wb + (size_t)o*NF + kk);
      #pragma unroll
      for (int j = 0; j < 8; ++j){
        acc[o][j] = fmaf(w4.x, xv[j].x, acc[o][j]);
        acc[o][j] = fmaf(w4.y, xv[j].y, acc[o][j]);
        acc[o][j] = fmaf(w4.z, xv[j].z, acc[o][j]);
        acc[o][j] = fmaf(w4.w, xv[j].w, acc[o][j]);
      }
    }
  }

  const float4 cbb4 = *(const float4*)(cbb + o4g*4);
  const float4 cw4  = *(const float4*)(clnw + o4g*4);
  const float4 cb4  = *(const float4*)(clnb + o4g*4);
  const float4 fw4  = *(const float4*)(flnw + o4g*4);
  const float4 fb4  = *(const float4*)(flnb + o4g*4);
  float4 rv[8];
  #pragma unroll
  for (int j = 0; j < 8; ++j){
    float cv[4] = {acc[0][j]+cbb4.x, acc[1][j]+cbb4.y, acc[2][j]+cbb4.z, acc[3][j]+cbb4.w};
    float s = cv[0]+cv[1]+cv[2]+cv[3];
    float s2 = cv[0]*cv[0]+cv[1]*cv[1]+cv[2]*cv[2]+cv[3]*cv[3];
    #pragma unroll
    for (int m = 1; m < 32; m <<= 1){ s += __shfl_xor(s, m, 64); s2 += __shfl_xor(s2, m, 64); }
    const float mu = s * (1.f/128.f);
    const float rs = rsqrtf(s2*(1.f/128.f) - mu*mu + 1e-5f);
    const float clw[4] = {cw4.x,cw4.y,cw4.z,cw4.w};
    const float clb[4] = {cb4.x,cb4.y,cb4.z,cb4.w};
    const float4 mv = *(const float4*)&xs[(t8*8+j)*NF + o4g*4];
    const float mvv[4] = {mv.x,mv.y,mv.z,mv.w};
    float res[4]; float rsum = 0.f, rsum2 = 0.f;
    #pragma unroll
    for (int i = 0; i < 4; ++i){
      const float cn = (cv[i] - mu)*rs*clw[i] + clb[i];
      const float g = 0.5f*cn*(1.f + erff(cn*0.70710678118f));
      res[i] = mvv[i] + g;
      rsum += res[i]; rsum2 += res[i]*res[i];
    }
    #pragma unroll
    for (int m = 1; m < 32; m <<= 1){ rsum += __shfl_xor(rsum, m, 64); rsum2 += __shfl_xor(rsum2, m, 64); }
    const float mu2 = rsum * (1.f/128.f);
    const float rs2 = rsqrtf(rsum2*(1.f/128.f) - mu2*mu2 + 1e-5f);
    const float flw[4] = {fw4.x,fw4.y,fw4.z,fw4.w};
    const float flb[4] = {fb4.x,fb4.y,fb4.z,fb4.w};
    rv[j] = make_float4((res[0]-mu2)*rs2*flw[0]+flb[0], (res[1]-mu2)*rs2*flw[1]+flb[1],
                        (res[2]-mu2)*rs2*flw[2]+flb[2], (res[3]-mu2)*rs2*flw[3]+flb[3]);
  }
  __syncthreads();   // xs (main) dead
  float* fs = xs;
  #pragma unroll
  for (int j = 0; j < 8; ++j)
    *(float4*)&fs[(t8*8+j)*NF + o4g*4] = rv[j];
  __syncthreads();

  // transposed out: per n-row, 64 consecutive rr
  {
    const int nn = tid >> 1, hh = tid & 1;
    #pragma unroll
    for (int q = 0; q < 8; ++q){
      const int tbase = hh*32 + q*4;
      const int tok = tok0 + tbase;
      if (tok >= NTOK) continue;
      const int b = tok / 30000, rr = tok - b*30000;
      float4 v;
      v.x = fs[(tbase+0)*NF + nn];
      v.y = fs[(tbase+1)*NF + nn];
      v.z = fs[(tbase+2)*NF + nn];
      v.w = fs[(tbase+3)*NF + nn];
      *(float4*)(out + ((size_t)(b*NF + nn))*30000 + rr) = v;
    }
  }
}

extern "C" void kernel_launch(void* const* d_in, const int* in_sizes, int n_in,
                              void* d_out, int out_size, void* d_ws, size_t ws_size,
                              hipStream_t stream){
  const float* x       = (const float*)d_in[0];
  const float* ln_w    = (const float*)d_in[1];
  const float* ln_b    = (const float*)d_in[2];
  const float* in_w    = (const float*)d_in[3];
  const float* in_b    = (const float*)d_in[4];
  const float* conv_w  = (const float*)d_in[5];
  const float* conv_b  = (const float*)d_in[6];
  const float* xp_w    = (const float*)d_in[7];
  const float* dtp_w   = (const float*)d_in[8];
  const float* dtp_b   = (const float*)d_in[9];
  const float* A_log   = (const float*)d_in[10];
  const float* Dv      = (const float*)d_in[11];
  const float* out_w   = (const float*)d_in[12];
  const float* out_b   = (const float*)d_in[13];
  const float* cb_w    = (const float*)d_in[14];
  const float* cb_b    = (const float*)d_in[15];
  const float* cb_ln_w = (const float*)d_in[16];
  const float* cb_ln_b = (const float*)d_in[17];
  const float* fin_ln_w= (const float*)d_in[18];
  const float* fin_ln_b= (const float*)d_in[19];
  float* out = (float*)d_out;

  const size_t SEQSZ = (size_t)BKS*TL*NF;        // 7,680,000 floats
  const size_t CHSZ  = (size_t)BKS*NCH*SD*NF;    // 2,949,120 floats
  const size_t DCBSZ = (size_t)NTOK*8;           // 480,000
  const size_t BCBSZ = (size_t)NTOK*24;          // 1,440,000
  float* ws   = (float*)d_ws;
  float* seq  = ws;
  float* zb   = ws + SEQSZ;
  float* xcc  = ws + 2*SEQSZ;
  float* dcb  = ws + 3*SEQSZ;
  float* bcb  = dcb + DCBSZ;
  float* ap   = bcb + BCBSZ;
  float* hfb  = ap + CHSZ;
  float* hinit= hfb + CHSZ;
  const size_t BASE = 3*SEQSZ + DCBSZ + BCBSZ + 3*CHSZ;
  if (ws_size < BASE*sizeof(float)) return;

  k_ingest<<<2*TL, 256, 0, stream>>>(x, seq);
  for (int l = 0; l < 4; ++l){
    k_front<<<BKS*NCB, 256, 0, stream>>>(seq,
        ln_w + l*NF, ln_b + l*NF,
        in_w + (size_t)l*2*NF*NF, in_b + (size_t)l*2*NF,
        conv_w + (size_t)l*NF*4, conv_b + l*NF,
        xp_w + (size_t)l*32*NF,
        dtp_w + (size_t)l*NF*8, dtp_b + l*NF,
        A_log + (size_t)l*NF*SD,
        zb, xcc, dcb, bcb, ap, hfb);
    k_scan_combine<<<BKS, NF, 0, stream>>>(ap, hfb, hinit);
    k_back<<<BKS*NCB, 256, 0, stream>>>(dcb, bcb, xcc, zb,
        dtp_w + (size_t)l*NF*8, dtp_b + l*NF,
        A_log + (size_t)l*NF*SD, hinit, Dv + l*NF,
        out_w + (size_t)l*NF*NF, out_b + l*NF, seq);
  }
  k_cross<<<CROSS_NBLK, 256, 0, stream>>>(seq, cb_w, cb_b, cb_ln_w, cb_ln_b, fin_ln_w, fin_ln_b, out);
}

// Round 4
// 1023.237 us; speedup vs baseline: 1.0076x; 1.0076x over previous
//
#include <hip/hip_runtime.h>
#include <math.h>

#define BKS 60      // B*K sequences
#define TL  1000    // T
#define NF  128     // N features
#define SD  12      // state dim S
#define NCH 32      // scan chunks of 32 (ap/hfb/hinit granularity)
#define NTOK (BKS*TL)
#define CL2 64      // front/back block token count (2 scan chunks)
#define NCB 16      // 64-token chunks per sequence
#define CROSS_NBLK ((NTOK + CL2 - 1)/CL2)   // 938

// row-keyed XOR swizzle (bits 2..4 of float col index) for [row][128] tiles
// where wave lanes span 8 rows 8-apart (t>>3 distinguishes them).
#define SRK(row) ((((row)>>3)&7)<<2)

__device__ __forceinline__ float siluf(float x){ return x / (1.f + __expf(-x)); }
__device__ __forceinline__ float softplusf(float x){
  if (x > 20.f) return x;
  float e = __expf(x);
  return (x < -20.f) ? e : __logf(1.f + e);
}

// ---- K0: x (B,N,T,K) -> seq (B*K, T, N), one block per (b,t)
__global__ __launch_bounds__(256) void k_ingest(const float* __restrict__ x, float* __restrict__ seq){
  const int b = blockIdx.x / TL, t = blockIdx.x % TL;
  __shared__ float tile[30*NF];
  for (int e = threadIdx.x; e < 30*NF; e += 256){
    int n = e / 30, k = e - n*30;
    tile[k*NF + n] = x[((size_t)(b*NF + n)*TL + t)*30 + k];
  }
  __syncthreads();
  const size_t base = ((size_t)b*30)*TL*NF + (size_t)t*NF;
  for (int e = threadIdx.x; e < 30*NF; e += 256){
    int k = e >> 7, n = e & 127;
    seq[base + (size_t)k*TL*NF + n] = tile[e];
  }
}

// ---- k_front: LN -> in_proj (256 outs) -> conv+silu -> xproj -> dt -> scan pass1.
// One 64-token chunk of one sequence per block. 960 blocks, 256 threads.
// R4: plain launch_bounds(256) (the (256,4) hint forced VGPR=64 -> acc[8][8] spilled
// to scratch, +20MB write traffic, 2x VALU stream). Halo hoisted out of the hot loop
// into a 192-thread mini-GEMM so the main 8ox8t k-loop has no predicate/extra regs.
__global__ __launch_bounds__(256) void k_front(
    const float* __restrict__ seq,
    const float* __restrict__ lnw, const float* __restrict__ lnb,
    const float* __restrict__ iw, const float* __restrict__ ib,
    const float* __restrict__ cw, const float* __restrict__ cb,
    const float* __restrict__ xw,
    const float* __restrict__ dw, const float* __restrict__ db,
    const float* __restrict__ alog,
    float* __restrict__ zb, float* __restrict__ xcc,
    float* __restrict__ dcb, float* __restrict__ bcb,
    float* __restrict__ ap, float* __restrict__ hfb){
  __shared__ float smem[10240];          // 40960 B
  float* xs   = smem;                    // [64][128] LN out, t-major, SRK-swizzled
  float* xh   = smem + 8192;             // [3][128] halo LN out (raw)
  float* sxcr = smem;                    // [67][128] raw xc (aliases xs+xh after GEMM)
  float* sxc  = smem;                    // [64][128] conv+silu out (in-place, SRK-swizzled)
  float* sdbc = smem + 8192;             // [64][32] dbc (after conv, rows 64..66 dead)

  const int bid = blockIdx.x;
  const int sq = bid >> 4, cb2 = bid & 15;
  const int t0 = cb2 * CL2;
  const int lim = (TL - t0 < CL2) ? (TL - t0) : CL2;
  const int tid = threadIdx.x;

  // ---- P0: LayerNorm for 64 main tokens + 3 halo tokens
  {
    const int j = tid >> 4, l16 = tid & 15;
    const float4 w0 = *(const float4*)(lnw + l16*8);
    const float4 w1 = *(const float4*)(lnw + l16*8 + 4);
    const float4 b0 = *(const float4*)(lnb + l16*8);
    const float4 b1 = *(const float4*)(lnb + l16*8 + 4);
    const float lw[8] = {w0.x,w0.y,w0.z,w0.w, w1.x,w1.y,w1.z,w1.w};
    const float lb[8] = {b0.x,b0.y,b0.z,b0.w, b1.x,b1.y,b1.z,b1.w};
    for (int it = 0; it < 4; ++it){
      const int t = j + 16*it;
      const bool valid = (t < lim);
      float v[8]; float s = 0.f, s2 = 0.f;
      if (valid){
        const float* sp = seq + ((size_t)sq*TL + t0 + t)*NF + l16*8;
        const float4 a0 = *(const float4*)sp;
        const float4 a1 = *(const float4*)(sp + 4);
        v[0]=a0.x; v[1]=a0.y; v[2]=a0.z; v[3]=a0.w;
        v[4]=a1.x; v[5]=a1.y; v[6]=a1.z; v[7]=a1.w;
        #pragma unroll
        for (int i = 0; i < 8; ++i){ s += v[i]; s2 += v[i]*v[i]; }
      } else {
        #pragma unroll
        for (int i = 0; i < 8; ++i) v[i] = 0.f;
      }
      #pragma unroll
      for (int m = 1; m < 16; m <<= 1){ s += __shfl_xor(s, m, 64); s2 += __shfl_xor(s2, m, 64); }
      const float mean = s * (1.f/128.f);
      const float rstd = rsqrtf(s2*(1.f/128.f) - mean*mean + 1e-5f);
      const int sk = SRK(t);
      float o[8];
      #pragma unroll
      for (int i = 0; i < 8; ++i)
        o[i] = valid ? ((v[i]-mean)*rstd*lw[i] + lb[i]) : 0.f;
      *(float4*)&xs[t*NF + ((l16*8)     ^ sk)] = make_float4(o[0],o[1],o[2],o[3]);
      *(float4*)&xs[t*NF + ((l16*8 + 4) ^ sk)] = make_float4(o[4],o[5],o[6],o[7]);
    }
    // halo: tokens t0-3..t0-1 -> xh rows 0..2 (raw layout)
    if (j < 3){
      const int tg2 = t0 - 3 + j;
      const bool valid = (tg2 >= 0);
      float v[8]; float s = 0.f, s2 = 0.f;
      if (valid){
        const float* sp = seq + ((size_t)sq*TL + tg2)*NF + l16*8;
        const float4 a0 = *(const float4*)sp;
        const float4 a1 = *(const float4*)(sp + 4);
        v[0]=a0.x; v[1]=a0.y; v[2]=a0.z; v[3]=a0.w;
        v[4]=a1.x; v[5]=a1.y; v[6]=a1.z; v[7]=a1.w;
        #pragma unroll
        for (int i = 0; i < 8; ++i){ s += v[i]; s2 += v[i]*v[i]; }
      } else {
        #pragma unroll
        for (int i = 0; i < 8; ++i) v[i] = 0.f;
      }
      #pragma unroll
      for (int m = 1; m < 16; m <<= 1){ s += __shfl_xor(s, m, 64); s2 += __shfl_xor(s2, m, 64); }
      const float mean = s * (1.f/128.f);
      const float rstd = rsqrtf(s2*(1.f/128.f) - mean*mean + 1e-5f);
      float o[8];
      #pragma unroll
      for (int i = 0; i < 8; ++i)
        o[i] = valid ? ((v[i]-mean)*rstd*lw[i] + lb[i]) : 0.f;
      *(float4*)&xh[j*NF + l16*8]     = make_float4(o[0],o[1],o[2],o[3]);
      *(float4*)&xh[j*NF + l16*8 + 4] = make_float4(o[4],o[5],o[6],o[7]);
    }
  }
  __syncthreads();

  // ---- P1: in_proj GEMM. og owns 8 output rows (og<16 -> xc, og>=16 -> z), tg owns 8 tokens.
  const int og = tid >> 3;     // 0..31
  const int tg = tid & 7;      // 0..7
  float acc[8][8];
  #pragma unroll
  for (int o = 0; o < 8; ++o)
    #pragma unroll
    for (int j = 0; j < 8; ++j) acc[o][j] = 0.f;
  const float* wb = iw + (size_t)(og*8)*NF;
  for (int k4 = 0; k4 < 32; ++k4){
    const int kk = k4*4;
    float4 xv[8];
    #pragma unroll
    for (int j = 0; j < 8; ++j)
      xv[j] = *(const float4*)&xs[(tg*8+j)*NF + (kk ^ (tg<<2))];
    #pragma unroll
    for (int o = 0; o < 8; ++o){
      const float4 w4 = *(const float4*)(wb + (size_t)o*NF + kk);
      #pragma unroll
      for (int j = 0; j < 8; ++j){
        acc[o][j] = fmaf(w4.x, xv[j].x, acc[o][j]);
        acc[o][j] = fmaf(w4.y, xv[j].y, acc[o][j]);
        acc[o][j] = fmaf(w4.z, xv[j].z, acc[o][j]);
        acc[o][j] = fmaf(w4.w, xv[j].w, acc[o][j]);
      }
    }
  }
  float bo[8];
  #pragma unroll
  for (int i = 0; i < 8; ++i) bo[i] = ib[og*8 + i];
  // z epilogue (register-only, before barrier)
  if (og >= 16){
    #pragma unroll
    for (int j = 0; j < 8; ++j){
      const int lt = tg*8 + j;
      if (lt >= lim) continue;
      float* dst = zb + ((size_t)sq*TL + t0 + lt)*NF + (og-16)*8;
      *(float4*)dst       = make_float4(acc[0][j]+bo[0], acc[1][j]+bo[1], acc[2][j]+bo[2], acc[3][j]+bo[3]);
      *(float4*)(dst + 4) = make_float4(acc[4][j]+bo[4], acc[5][j]+bo[5], acc[6][j]+bo[6], acc[7][j]+bo[7]);
    }
  }
  // halo mini-GEMM: 192 threads, each 2 outs (oc, oc+64) for halo row hh. Reads xh.
  float hv0 = 0.f, hv1 = 0.f;
  const int hh = tid >> 6;       // 0..2 for tid<192
  const int oc = tid & 63;
  if (tid < 192){
    for (int k4 = 0; k4 < 32; ++k4){
      const int kk = k4*4;
      const float4 xh4 = *(const float4*)&xh[hh*NF + kk];
      const float4 wa = *(const float4*)(iw + (size_t)oc*NF + kk);
      const float4 wc = *(const float4*)(iw + (size_t)(oc+64)*NF + kk);
      hv0 = fmaf(wa.w, xh4.w, fmaf(wa.z, xh4.z, fmaf(wa.y, xh4.y, fmaf(wa.x, xh4.x, hv0))));
      hv1 = fmaf(wc.w, xh4.w, fmaf(wc.z, xh4.z, fmaf(wc.y, xh4.y, fmaf(wc.x, xh4.x, hv1))));
    }
  }
  __syncthreads();   // xs/xh reads done -> sxcr may be written
  if (og < 16){
    #pragma unroll
    for (int j = 0; j < 8; ++j){
      const int row = tg*8 + j + 3;
      const int sk = SRK(row);
      *(float4*)&sxcr[row*NF + ((og*8)     ^ sk)] = make_float4(acc[0][j]+bo[0], acc[1][j]+bo[1], acc[2][j]+bo[2], acc[3][j]+bo[3]);
      *(float4*)&sxcr[row*NF + ((og*8 + 4) ^ sk)] = make_float4(acc[4][j]+bo[4], acc[5][j]+bo[5], acc[6][j]+bo[6], acc[7][j]+bo[7]);
    }
  }
  if (tid < 192){
    const bool hvalid = (t0 - 3 + hh) >= 0;
    // rows 0..2: SRK==0 -> raw layout
    sxcr[hh*NF + oc]      = hvalid ? (hv0 + ib[oc])      : 0.f;
    sxcr[hh*NF + oc + 64] = hvalid ? (hv1 + ib[oc + 64]) : 0.f;
  }
  __syncthreads();

  // ---- P2: conv + silu, in place (two halves; reg-stage inputs, barrier, write)
  for (int half = 0; half < 2; ++half){
    float4 xin[4][4];
    #pragma unroll
    for (int i = 0; i < 4; ++i){
      const int e4 = tid + i*256;
      const int j2 = half*32 + (e4 >> 5);
      const int n4 = (e4 & 31) << 2;
      #pragma unroll
      for (int q = 0; q < 4; ++q){
        const int row = j2 + q;
        xin[i][q] = *(const float4*)&sxcr[row*NF + (n4 ^ SRK(row))];
      }
    }
    __syncthreads();
    #pragma unroll
    for (int i = 0; i < 4; ++i){
      const int e4 = tid + i*256;
      const int j2 = half*32 + (e4 >> 5);
      const int n4 = (e4 & 31) << 2;
      const float4 c0 = *(const float4*)(cw + (size_t)(n4+0)*4);
      const float4 c1 = *(const float4*)(cw + (size_t)(n4+1)*4);
      const float4 c2 = *(const float4*)(cw + (size_t)(n4+2)*4);
      const float4 c3 = *(const float4*)(cw + (size_t)(n4+3)*4);
      float4 a = *(const float4*)(cb + n4);
      a.x = fmaf(xin[i][3].x, c0.w, fmaf(xin[i][2].x, c0.z, fmaf(xin[i][1].x, c0.y, fmaf(xin[i][0].x, c0.x, a.x))));
      a.y = fmaf(xin[i][3].y, c1.w, fmaf(xin[i][2].y, c1.z, fmaf(xin[i][1].y, c1.y, fmaf(xin[i][0].y, c1.x, a.y))));
      a.z = fmaf(xin[i][3].z, c2.w, fmaf(xin[i][2].z, c2.z, fmaf(xin[i][1].z, c2.y, fmaf(xin[i][0].z, c2.x, a.z))));
      a.w = fmaf(xin[i][3].w, c3.w, fmaf(xin[i][2].w, c3.z, fmaf(xin[i][1].w, c3.y, fmaf(xin[i][0].w, c3.x, a.w))));
      a.x = siluf(a.x); a.y = siluf(a.y); a.z = siluf(a.z); a.w = siluf(a.w);
      *(float4*)&sxc[j2*NF + (n4 ^ SRK(j2))] = a;
      if (j2 < lim) *(float4*)(xcc + ((size_t)sq*TL + t0 + j2)*NF + n4) = a;
    }
    __syncthreads();
  }

  // ---- P3: xproj -> sdbc[64][32] (w from global)
  {
    const int og2 = tid >> 5;   // 0..7, outs og2*4..+3
    const int tg2 = tid & 31;   // tokens tg2*2, tg2*2+1
    const int ta = tg2*2, tb = tg2*2 + 1;
    const int ska = SRK(ta), skb = SRK(tb);
    float pa[4][2];
    #pragma unroll
    for (int o = 0; o < 4; ++o){ pa[o][0] = 0.f; pa[o][1] = 0.f; }
    const float* xwb = xw + (size_t)(og2*4)*NF;
    for (int k4 = 0; k4 < 32; ++k4){
      const int kk = k4*4;
      const float4 xv0 = *(const float4*)&sxc[ta*NF + (kk ^ ska)];
      const float4 xv1 = *(const float4*)&sxc[tb*NF + (kk ^ skb)];
      #pragma unroll
      for (int o = 0; o < 4; ++o){
        const float4 w4 = *(const float4*)(xwb + (size_t)o*NF + kk);
        pa[o][0] = fmaf(w4.w, xv0.w, fmaf(w4.z, xv0.z, fmaf(w4.y, xv0.y, fmaf(w4.x, xv0.x, pa[o][0]))));
        pa[o][1] = fmaf(w4.w, xv1.w, fmaf(w4.z, xv1.z, fmaf(w4.y, xv1.y, fmaf(w4.x, xv1.x, pa[o][1]))));
      }
    }
    *(float4*)&sdbc[ta*32 + og2*4] = make_float4(pa[0][0],pa[1][0],pa[2][0],pa[3][0]);
    *(float4*)&sdbc[tb*32 + og2*4] = make_float4(pa[0][1],pa[1][1],pa[2][1],pa[3][1]);
  }
  __syncthreads();

  // ---- P4: dcb/bcb global writes + scan pass1 (dt computed in-thread)
  if (tid < 128){
    const int t = tid >> 1, q = tid & 1;
    if (t < lim)
      *(float4*)(dcb + ((size_t)sq*TL + t0 + t)*8 + q*4) = *(const float4*)&sdbc[t*32 + q*4];
  }
  for (int e = tid; e < 384; e += 256){
    const int t = e / 6, q = e - t*6;
    if (t < lim)
      *(float4*)(bcb + ((size_t)sq*TL + t0 + t)*24 + q*4) = *(const float4*)&sdbc[t*32 + 8 + q*4];
  }
  {
    const int n = tid & 127, ch = tid >> 7;
    float Av[SD];
    {
      const float4 a0 = *(const float4*)(alog + (size_t)n*SD);
      const float4 a1 = *(const float4*)(alog + (size_t)n*SD + 4);
      const float4 a2 = *(const float4*)(alog + (size_t)n*SD + 8);
      const float t_[SD] = {a0.x,a0.y,a0.z,a0.w, a1.x,a1.y,a1.z,a1.w, a2.x,a2.y,a2.z,a2.w};
      #pragma unroll
      for (int s = 0; s < SD; ++s) Av[s] = -__expf(t_[s]);
    }
    const float4 dw0 = *(const float4*)(dw + (size_t)n*8);
    const float4 dw1 = *(const float4*)(dw + (size_t)n*8 + 4);
    const float dbn = db[n];
    int steps = lim - ch*32; if (steps < 0) steps = 0; if (steps > 32) steps = 32;
    float h[SD]; float dts = 0.f;
    #pragma unroll
    for (int s = 0; s < SD; ++s) h[s] = 0.f;
    for (int tt = 0; tt < steps; ++tt){
      const int t = ch*32 + tt;
      const float4 q0 = *(const float4*)&sdbc[t*32];
      const float4 q1 = *(const float4*)&sdbc[t*32 + 4];
      float da = dbn;
      da = fmaf(q0.x,dw0.x, da); da = fmaf(q0.y,dw0.y, da);
      da = fmaf(q0.z,dw0.z, da); da = fmaf(q0.w,dw0.w, da);
      da = fmaf(q1.x,dw1.x, da); da = fmaf(q1.y,dw1.y, da);
      da = fmaf(q1.z,dw1.z, da); da = fmaf(q1.w,dw1.w, da);
      const float dtv = softplusf(da);
      const float xcv = sxc[t*NF + (n ^ SRK(t))];
      const float4 B0 = *(const float4*)&sdbc[t*32 + 8];
      const float4 B1 = *(const float4*)&sdbc[t*32 + 12];
      const float4 B2 = *(const float4*)&sdbc[t*32 + 16];
      const float Bv[SD] = {B0.x,B0.y,B0.z,B0.w, B1.x,B1.y,B1.z,B1.w, B2.x,B2.y,B2.z,B2.w};
      const float dx = dtv * xcv;
      dts += dtv;
      #pragma unroll
      for (int s = 0; s < SD; ++s){
        const float dA = __expf(dtv*Av[s]);
        h[s] = fmaf(dA, h[s], dx*Bv[s]);
      }
    }
    const size_t base = ((size_t)(sq*NCH + cb2*2 + ch))*SD*NF + n;
    #pragma unroll
    for (int s = 0; s < SD; ++s){
      ap [base + s*NF] = __expf(Av[s]*dts);
      hfb[base + s*NF] = h[s];
    }
  }
}

// ---- K3b: sequential combine across chunks (unchanged)
__global__ __launch_bounds__(128) void k_scan_combine(
    const float* __restrict__ ap, const float* __restrict__ hfb, float* __restrict__ hinit){
  const int sq = blockIdx.x;
  const int n = threadIdx.x;
  float h[SD];
  #pragma unroll
  for (int s = 0; s < SD; ++s) h[s] = 0.f;
  for (int c = 0; c < NCH; ++c){
    const size_t base = ((size_t)sq*NCH + c)*SD*NF + n;
    #pragma unroll
    for (int s = 0; s < SD; ++s){
      hinit[base + s*NF] = h[s];
      h[s] = fmaf(ap[base + s*NF], h[s], hfb[base + s*NF]);
    }
  }
}

// ---- k_back: scan pass2 (y -> LDS) -> output GEMM -> seq += y@ow^T+ob.
// R4: plain launch_bounds(256); GEMM is 128 outs so no K-split: 16og x 16tg,
// acc[8][4] = 32 regs (was 64 + spill), no partial-sum LDS phase, one barrier fewer.
__global__ __launch_bounds__(256) void k_back(
    const float* __restrict__ dcb, const float* __restrict__ bcb,
    const float* __restrict__ xcc, const float* __restrict__ zb,
    const float* __restrict__ dw, const float* __restrict__ db,
    const float* __restrict__ alog, const float* __restrict__ hinit,
    const float* __restrict__ Dv,
    const float* __restrict__ ow, const float* __restrict__ ob,
    float* __restrict__ seq){
  __shared__ float xs[CL2*NF];   // 32768 B; y (SRK-swizzled)
  const int bid = blockIdx.x;
  const int sq = bid >> 4, cb2 = bid & 15;
  const int t0 = cb2 * CL2;
  const int lim = (TL - t0 < CL2) ? (TL - t0) : CL2;
  const int tid = threadIdx.x;

  // ---- P0: scan pass2 + gate, write y to LDS
  {
    const int n = tid & 127, ch = tid >> 7;
    float Av[SD];
    {
      const float4 a0 = *(const float4*)(alog + (size_t)n*SD);
      const float4 a1 = *(const float4*)(alog + (size_t)n*SD + 4);
      const float4 a2 = *(const float4*)(alog + (size_t)n*SD + 8);
      const float t_[SD] = {a0.x,a0.y,a0.z,a0.w, a1.x,a1.y,a1.z,a1.w, a2.x,a2.y,a2.z,a2.w};
      #pragma unroll
      for (int s = 0; s < SD; ++s) Av[s] = -__expf(t_[s]);
    }
    const float4 dw0 = *(const float4*)(dw + (size_t)n*8);
    const float4 dw1 = *(const float4*)(dw + (size_t)n*8 + 4);
    const float dbn = db[n];
    const float dvn = Dv[n];
    float h[SD];
    {
      const size_t hb = ((size_t)(sq*NCH + cb2*2 + ch))*SD*NF + n;
      #pragma unroll
      for (int s = 0; s < SD; ++s) h[s] = hinit[hb + s*NF];
    }
    int steps = lim - ch*32; if (steps < 0) steps = 0; if (steps > 32) steps = 32;
    for (int tt = 0; tt < steps; ++tt){
      const int t = ch*32 + tt;
      const size_t gt = (size_t)sq*TL + t0 + t;
      const float4 d0 = *(const float4*)(dcb + gt*8);
      const float4 d1 = *(const float4*)(dcb + gt*8 + 4);
      float da = dbn;
      da = fmaf(d0.x,dw0.x, da); da = fmaf(d0.y,dw0.y, da);
      da = fmaf(d0.z,dw0.z, da); da = fmaf(d0.w,dw0.w, da);
      da = fmaf(d1.x,dw1.x, da); da = fmaf(d1.y,dw1.y, da);
      da = fmaf(d1.z,dw1.z, da); da = fmaf(d1.w,dw1.w, da);
      const float dtv = softplusf(da);
      const float xcv = xcc[gt*NF + n];
      const float zv  = zb [gt*NF + n];
      const float4 B0 = *(const float4*)(bcb + gt*24);
      const float4 B1 = *(const float4*)(bcb + gt*24 + 4);
      const float4 B2 = *(const float4*)(bcb + gt*24 + 8);
      const float4 C0 = *(const float4*)(bcb + gt*24 + 12);
      const float4 C1 = *(const float4*)(bcb + gt*24 + 16);
      const float4 C2 = *(const float4*)(bcb + gt*24 + 20);
      const float Bv[SD] = {B0.x,B0.y,B0.z,B0.w, B1.x,B1.y,B1.z,B1.w, B2.x,B2.y,B2.z,B2.w};
      const float Cv[SD] = {C0.x,C0.y,C0.z,C0.w, C1.x,C1.y,C1.z,C1.w, C2.x,C2.y,C2.z,C2.w};
      const float dx = dtv * xcv;
      float y = 0.f;
      #pragma unroll
      for (int s = 0; s < SD; ++s){
        const float dA = __expf(dtv*Av[s]);
        h[s] = fmaf(dA, h[s], dx*Bv[s]);
        y = fmaf(h[s], Cv[s], y);
      }
      const float yf = fmaf(dvn, xcv, y) * siluf(zv);
      xs[t*NF + (n ^ SRK(t))] = yf;
    }
  }
  // zero rows beyond lim (last chunk only)
  if (lim < CL2){
    for (int e = tid; e < (CL2 - lim)*NF; e += 256) xs[lim*NF + e] = 0.f;
  }
  __syncthreads();

  // ---- P1: GEMM seq += y @ ow^T + ob.  8o x 4t tile, full K=128, no split.
  {
    const int og = tid >> 4;     // 0..15, outs og*8..+7
    const int tg = tid & 15;     // 0..15, toks tg*4..+3
    float acc[8][4];
    #pragma unroll
    for (int o = 0; o < 8; ++o)
      #pragma unroll
      for (int j = 0; j < 4; ++j) acc[o][j] = 0.f;
    const float* owb = ow + (size_t)(og*8)*NF;
    for (int k4 = 0; k4 < 32; ++k4){
      const int kk = k4*4;
      float4 xv[4];
      #pragma unroll
      for (int j = 0; j < 4; ++j){
        const int row = tg*4 + j;
        xv[j] = *(const float4*)&xs[row*NF + (kk ^ SRK(row))];
      }
      #pragma unroll
      for (int o = 0; o < 8; ++o){
        const float4 w4 = *(const float4*)(owb + (size_t)o*NF + kk);
        #pragma unroll
        for (int j = 0; j < 4; ++j){
          acc[o][j] = fmaf(w4.x, xv[j].x, acc[o][j]);
          acc[o][j] = fmaf(w4.y, xv[j].y, acc[o][j]);
          acc[o][j] = fmaf(w4.z, xv[j].z, acc[o][j]);
          acc[o][j] = fmaf(w4.w, xv[j].w, acc[o][j]);
        }
      }
    }
    float bo[8];
    #pragma unroll
    for (int i = 0; i < 8; ++i) bo[i] = ob[og*8 + i];
    #pragma unroll
    for (int j = 0; j < 4; ++j){
      const int lt = tg*4 + j;
      if (lt >= lim) continue;
      float* dst = seq + ((size_t)sq*TL + t0 + lt)*NF + og*8;
      float4 s0 = *(float4*)dst;
      float4 s1 = *(float4*)(dst + 4);
      s0.x += acc[0][j]+bo[0]; s0.y += acc[1][j]+bo[1];
      s0.z += acc[2][j]+bo[2]; s0.w += acc[3][j]+bo[3];
      s1.x += acc[4][j]+bo[4]; s1.y += acc[5][j]+bo[5];
      s1.z += acc[6][j]+bo[6]; s1.w += acc[7][j]+bo[7];
      *(float4*)dst = s0;
      *(float4*)(dst + 4) = s1;
    }
  }
}

// ---- k_cross: cross GEMM -> LN -> gelu -> +main -> LN -> transposed out. 64 tok/block.
__global__ __launch_bounds__(256) void k_cross(
    const float* __restrict__ seq,
    const float* __restrict__ cbw, const float* __restrict__ cbb,
    const float* __restrict__ clnw, const float* __restrict__ clnb,
    const float* __restrict__ flnw, const float* __restrict__ flnb,
    float* __restrict__ out){
  __shared__ float xs[CL2*NF];   // main (gathered), t-major raw; aliased as fs after LN
  const int tid = threadIdx.x;
  const int tok0 = blockIdx.x * CL2;

  // stage main (gather)
  #pragma unroll
  for (int i = 0; i < 8; ++i){
    const int nq = (tid & 15) + ((i >> 2) << 4);        // 0..31
    const int r  = ((tid >> 4) & 15) + ((i & 3) << 4);  // 0..63
    const int tok = tok0 + r;
    float4 v = make_float4(0.f,0.f,0.f,0.f);
    if (tok < NTOK){
      const int b = tok / 30000, rr = tok - b*30000;
      const int t = rr / 30, k = rr - t*30;
      v = *(const float4*)(seq + ((size_t)(b*30 + k)*TL + t)*NF + nq*4);
    }
    *(float4*)&xs[r*NF + nq*4] = v;
  }
  __syncthreads();

  const int o4g = tid & 31, t8 = tid >> 5;   // 4 outs, 8 tokens per thread
  float acc[4][8];
  #pragma unroll
  for (int o = 0; o < 4; ++o)
    #pragma unroll
    for (int j = 0; j < 8; ++j) acc[o][j] = 0.f;
  const float* wb = cbw + (size_t)(o4g*4)*NF;
  for (int k4 = 0; k4 < 32; ++k4){
    const int kk = k4*4;
    float4 xv[8];
    #pragma unroll
    for (int j = 0; j < 8; ++j)
      xv[j] = *(const float4*)&xs[(t8*8+j)*NF + kk];
    #pragma unroll
    for (int o = 0; o < 4; ++o){
      const float4 w4 = *(const float4*)(wb + (size_t)o*NF + kk);
      #pragma unroll
      for (int j = 0; j < 8; ++j){
        acc[o][j] = fmaf(w4.x, xv[j].x, acc[o][j]);
        acc[o][j] = fmaf(w4.y, xv[j].y, acc[o][j]);
        acc[o][j] = fmaf(w4.z, xv[j].z, acc[o][j]);
        acc[o][j] = fmaf(w4.w, xv[j].w, acc[o][j]);
      }
    }
  }

  const float4 cbb4 = *(const float4*)(cbb + o4g*4);
  const float4 cw4  = *(const float4*)(clnw + o4g*4);
  const float4 cb4  = *(const float4*)(clnb + o4g*4);
  const float4 fw4  = *(const float4*)(flnw + o4g*4);
  const float4 fb4  = *(const float4*)(flnb + o4g*4);
  float4 rv[8];
  #pragma unroll
  for (int j = 0; j < 8; ++j){
    float cv[4] = {acc[0][j]+cbb4.x, acc[1][j]+cbb4.y, acc[2][j]+cbb4.z, acc[3][j]+cbb4.w};
    float s = cv[0]+cv[1]+cv[2]+cv[3];
    float s2 = cv[0]*cv[0]+cv[1]*cv[1]+cv[2]*cv[2]+cv[3]*cv[3];
    #pragma unroll
    for (int m = 1; m < 32; m <<= 1){ s += __shfl_xor(s, m, 64); s2 += __shfl_xor(s2, m, 64); }
    const float mu = s * (1.f/128.f);
    const float rs = rsqrtf(s2*(1.f/128.f) - mu*mu + 1e-5f);
    const float clw[4] = {cw4.x,cw4.y,cw4.z,cw4.w};
    const float clb[4] = {cb4.x,cb4.y,cb4.z,cb4.w};
    const float4 mv = *(const float4*)&xs[(t8*8+j)*NF + o4g*4];
    const float mvv[4] = {mv.x,mv.y,mv.z,mv.w};
    float res[4]; float rsum = 0.f, rsum2 = 0.f;
    #pragma unroll
    for (int i = 0; i < 4; ++i){
      const float cn = (cv[i] - mu)*rs*clw[i] + clb[i];
      const float g = 0.5f*cn*(1.f + erff(cn*0.70710678118f));
      res[i] = mvv[i] + g;
      rsum += res[i]; rsum2 += res[i]*res[i];
    }
    #pragma unroll
    for (int m = 1; m < 32; m <<= 1){ rsum += __shfl_xor(rsum, m, 64); rsum2 += __shfl_xor(rsum2, m, 64); }
    const float mu2 = rsum * (1.f/128.f);
    const float rs2 = rsqrtf(rsum2*(1.f/128.f) - mu2*mu2 + 1e-5f);
    const float flw[4] = {fw4.x,fw4.y,fw4.z,fw4.w};
    const float flb[4] = {fb4.x,fb4.y,fb4.z,fb4.w};
    rv[j] = make_float4((res[0]-mu2)*rs2*flw[0]+flb[0], (res[1]-mu2)*rs2*flw[1]+flb[1],
                        (res[2]-mu2)*rs2*flw[2]+flb[2], (res[3]-mu2)*rs2*flw[3]+flb[3]);
  }
  __syncthreads();   // xs (main) dead
  float* fs = xs;
  #pragma unroll
  for (int j = 0; j < 8; ++j)
    *(float4*)&fs[(t8*8+j)*NF + o4g*4] = rv[j];
  __syncthreads();

  // transposed out: per n-row, 64 consecutive rr
  {
    const int nn = tid >> 1, hh = tid & 1;
    #pragma unroll
    for (int q = 0; q < 8; ++q){
      const int tbase = hh*32 + q*4;
      const int tok = tok0 + tbase;
      if (tok >= NTOK) continue;
      const int b = tok / 30000, rr = tok - b*30000;
      float4 v;
      v.x = fs[(tbase+0)*NF + nn];
      v.y = fs[(tbase+1)*NF + nn];
      v.z = fs[(tbase+2)*NF + nn];
      v.w = fs[(tbase+3)*NF + nn];
      *(float4*)(out + ((size_t)(b*NF + nn))*30000 + rr) = v;
    }
  }
}

extern "C" void kernel_launch(void* const* d_in, const int* in_sizes, int n_in,
                              void* d_out, int out_size, void* d_ws, size_t ws_size,
                              hipStream_t stream){
  const float* x       = (const float*)d_in[0];
  const float* ln_w    = (const float*)d_in[1];
  const float* ln_b    = (const float*)d_in[2];
  const float* in_w    = (const float*)d_in[3];
  const float* in_b    = (const float*)d_in[4];
  const float* conv_w  = (const float*)d_in[5];
  const float* conv_b  = (const float*)d_in[6];
  const float* xp_w    = (const float*)d_in[7];
  const float* dtp_w   = (const float*)d_in[8];
  const float* dtp_b   = (const float*)d_in[9];
  const float* A_log   = (const float*)d_in[10];
  const float* Dv      = (const float*)d_in[11];
  const float* out_w   = (const float*)d_in[12];
  const float* out_b   = (const float*)d_in[13];
  const float* cb_w    = (const float*)d_in[14];
  const float* cb_b    = (const float*)d_in[15];
  const float* cb_ln_w = (const float*)d_in[16];
  const float* cb_ln_b = (const float*)d_in[17];
  const float* fin_ln_w= (const float*)d_in[18];
  const float* fin_ln_b= (const float*)d_in[19];
  float* out = (float*)d_out;

  const size_t SEQSZ = (size_t)BKS*TL*NF;        // 7,680,000 floats
  const size_t CHSZ  = (size_t)BKS*NCH*SD*NF;    // 2,949,120 floats
  const size_t DCBSZ = (size_t)NTOK*8;           // 480,000
  const size_t BCBSZ = (size_t)NTOK*24;          // 1,440,000
  float* ws   = (float*)d_ws;
  float* seq  = ws;
  float* zb   = ws + SEQSZ;
  float* xcc  = ws + 2*SEQSZ;
  float* dcb  = ws + 3*SEQSZ;
  float* bcb  = dcb + DCBSZ;
  float* ap   = bcb + BCBSZ;
  float* hfb  = ap + CHSZ;
  float* hinit= hfb + CHSZ;
  const size_t BASE = 3*SEQSZ + DCBSZ + BCBSZ + 3*CHSZ;
  if (ws_size < BASE*sizeof(float)) return;

  k_ingest<<<2*TL, 256, 0, stream>>>(x, seq);
  for (int l = 0; l < 4; ++l){
    k_front<<<BKS*NCB, 256, 0, stream>>>(seq,
        ln_w + l*NF, ln_b + l*NF,
        in_w + (size_t)l*2*NF*NF, in_b + (size_t)l*2*NF,
        conv_w + (size_t)l*NF*4, conv_b + l*NF,
        xp_w + (size_t)l*32*NF,
        dtp_w + (size_t)l*NF*8, dtp_b + l*NF,
        A_log + (size_t)l*NF*SD,
        zb, xcc, dcb, bcb, ap, hfb);
    k_scan_combine<<<BKS, NF, 0, stream>>>(ap, hfb, hinit);
    k_back<<<BKS*NCB, 256, 0, stream>>>(dcb, bcb, xcc, zb,
        dtp_w + (size_t)l*NF*8, dtp_b + l*NF,
        A_log + (size_t)l*NF*SD, hinit, Dv + l*NF,
        out_w + (size_t)l*NF*NF, out_b + l*NF, seq);
  }
  k_cross<<<CROSS_NBLK, 256, 0, stream>>>(seq, cb_w, cb_b, cb_ln_w, cb_ln_b, fin_ln_w, fin_ln_b, out);
}